// Round 11
// baseline (289.982 us; speedup 1.0000x reference)
//
#include <hip/hip_runtime.h>
#include <hip/hip_bf16.h>

// Spectral_Atten: q,k,v = dwconv3x3(conv1x1(x,W*)); channel-attention per head;
// out = conv1x1(attn@v, Wp).
// R1: split latency-bound fused dwgram (554->398). R2: k_mmat retile (->281).
// R3-R10: conv1 pinned ~112us across 6 structural variants (store patterns,
//   XCD swizzle, occupancy, phased preload all falsified; R8/R9 spilled).
//   Accepting conv1 ~112us; attacking the ~150us tail.
// R11: revert conv1/k_out MFMA to R5-exact; DELETE k_dw's v pass; k_out
//   computes dw(v) on the fly while staging Bt (same bf16 rounding point).
//   Saves 98MB HBM round-trip; k_out's v0 reads are L2/L3-warm.

using bf16x8 = __attribute__((ext_vector_type(8))) short;
using f32x4  = __attribute__((ext_vector_type(4))) float;
using fvec4  = __attribute__((ext_vector_type(4))) float;

#define NB     8
#define CDIM   192
#define NHEADS 6
#define IMGW   128
#define NPIX   16384

__device__ __forceinline__ float b2f(unsigned short u){
  return __uint_as_float(((unsigned int)u) << 16);
}
__device__ __forceinline__ unsigned short f2b(float f){
  unsigned int x = __float_as_uint(f);
  return (unsigned short)((x + 0x7FFFu + ((x >> 16) & 1u)) >> 16);
}
__device__ __forceinline__ float ldT(const void* p, size_t i, int isbf){
  return isbf ? b2f(((const unsigned short*)p)[i]) : ((const float*)p)[i];
}
__device__ __forceinline__ f32x4 MF(bf16x8 a, bf16x8 b, f32x4 c){
  return __builtin_amdgcn_mfma_f32_16x16x32_bf16(a, b, c, 0, 0, 0);
}

// ---- dtype detector (bf16 vs fp32 device buffers)
__global__ void k_detect(const unsigned short* x, int* flag){
  int l = threadIdx.x;
  int cnt = 0;
#pragma unroll
  for (int i = 0; i < 2; ++i){
    unsigned short u = x[(l*2 + i)*2];
    float a = fabsf(b2f(u));
    if (a == 0.f || (a > 1e-4f && a < 20.f)) ++cnt;
  }
  int tot = __popcll(__ballot(cnt >= 1)) + __popcll(__ballot(cnt >= 2));
  if (l == 0) *flag = (tot > 64) ? 1 : 0;
}

// ---- pack Wq,Wk,Wv into stacked bf16 [576][192]
__global__ __launch_bounds__(256) void k_prep(const void* Wq, const void* Wk, const void* Wv,
    unsigned short* Wqkv, const int* flag){
  int i = blockIdx.x*256 + threadIdx.x;
  if (i >= 576*192) return;
  int isbf = *flag;
  int m = i / 192, kk = i % 192;
  int t = m / 192;
  const void* W = (t == 0) ? Wq : (t == 1) ? Wk : Wv;
  Wqkv[i] = f2b(ldT(W, (size_t)(m % 192)*192 + kk, isbf));
}

// ---- fused triple 1x1 conv (R5-exact): q0,k0,v0 channel-major.
__global__ __launch_bounds__(256) void k_conv1(const void* x, const unsigned short* Wqkv,
    unsigned short* q0, unsigned short* k0, unsigned short* v0, const int* flag){
  __shared__ unsigned short Bt[64][200];     // x-tile [px][k^s]
  __shared__ unsigned short outb[192][72];   // epilogue tile [m][px]
  int tid = threadIdx.x;
  int ntr = blockIdx.x, b = blockIdx.y;
  int nt = (ntr & 7)*32 + (ntr >> 3);        // XCD grouping
  int n0 = nt * 64;
  int isbf = *flag;
  if (isbf){
    const unsigned short* xs = (const unsigned short*)x;
    for (int r = tid; r < 1536; r += 256){
      int k = r >> 3, j8 = (r & 7) * 8;
      int s = (r & 7) << 3;
      bf16x8 v = *(const bf16x8*)(xs + (size_t)(b*CDIM + k)*NPIX + n0 + j8);
      int kx = k ^ s;
#pragma unroll
      for (int i = 0; i < 8; ++i) Bt[j8+i][kx] = (unsigned short)v[i];
    }
  } else {
    const float* xf = (const float*)x;
    for (int r = tid; r < 3072; r += 256){
      int k = r >> 4, j4 = (r & 15) * 4;
      int s = ((j4 >> 3) & 7) << 3;
      fvec4 v = *(const fvec4*)(xf + (size_t)(b*CDIM + k)*NPIX + n0 + j4);
      int kx = k ^ s;
#pragma unroll
      for (int i = 0; i < 4; ++i) Bt[j4+i][kx] = f2b(v[i]);
    }
  }
  __syncthreads();
  int w = tid >> 6, l = tid & 63, lr = l & 15, lk = l >> 4;
#pragma unroll 1
  for (int t = 0; t < 3; ++t){
    f32x4 acc[3][4] = {};
    for (int kc = 0; kc < 6; ++kc){
      bf16x8 af[3];
#pragma unroll
      for (int g = 0; g < 3; ++g)
        af[g] = *(const bf16x8*)(Wqkv + ((size_t)t*CDIM + g*64 + w*16 + lr)*CDIM + kc*32 + lk*8);
#pragma unroll
      for (int nf = 0; nf < 4; ++nf){
        int nrow = nf*16 + lr;
        int s = ((nrow >> 3) & 7) << 3;
        bf16x8 bfv = *(const bf16x8*)(&Bt[nrow][(kc*32 + lk*8) ^ s]);
#pragma unroll
        for (int g = 0; g < 3; ++g) acc[g][nf] = MF(af[g], bfv, acc[g][nf]);
      }
    }
    __syncthreads();   // prev t's cooperative store done; outb free
#pragma unroll
    for (int g = 0; g < 3; ++g)
#pragma unroll
      for (int nf = 0; nf < 4; ++nf)
#pragma unroll
        for (int r = 0; r < 4; ++r)
          outb[g*64 + w*16 + lk*4 + r][nf*16 + lr] = f2b(acc[g][nf][r]);
    __syncthreads();
    unsigned short* dst = ((t == 0) ? q0 : (t == 1) ? k0 : v0) + (size_t)b*CDIM*NPIX;
    for (int e = tid; e < 1536; e += 256){
      int m = e >> 3, p8 = (e & 7) * 8;
      *(bf16x8*)(dst + (size_t)m*NPIX + n0 + p8) = *(const bf16x8*)(&outb[m][p8]);
    }
  }
}

// ---- depthwise 3x3 for q,k ONLY (R11: v handled in k_out), in-place.
__global__ __launch_bounds__(256) void k_dw(unsigned short* q0, unsigned short* k0,
    const void* wqd, const void* wkd, float* Nsq, const int* flag){
  __shared__ unsigned short img[128][136];
  __shared__ unsigned short outb[128][136];
  __shared__ float wred[4];
  int tid = threadIdx.x;
  int t = blockIdx.x, c = blockIdx.y, b = blockIdx.z;
  int isbf = *flag;
  unsigned short* base = ((t == 0) ? q0 : k0) + (size_t)(b*CDIM + c)*NPIX;
  const void* wd = (t == 0) ? wqd : wkd;
  float w9[9];
#pragma unroll
  for (int e = 0; e < 9; ++e) w9[e] = ldT(wd, (size_t)c*9 + e, isbf);
  for (int r = tid; r < 2048; r += 256){
    int row = r >> 4, col8 = (r & 15)*8;
    *(bf16x8*)(&img[row][col8]) = *(const bf16x8*)(base + row*IMGW + col8);
  }
  __syncthreads();
  int tr = tid >> 2, tc = tid & 3;
  int c0 = tc * 32, r0 = tr * 2;
  const bf16x8 zv = {0,0,0,0,0,0,0,0};
  int  rowi[4]; bool valid[4];
  bf16x8 cur[4], nxt[4];
  float carry[4];
#pragma unroll
  for (int d = 0; d < 4; ++d){
    rowi[d] = r0 - 1 + d;
    valid[d] = (rowi[d] >= 0) && (rowi[d] < 128);
    cur[d] = valid[d] ? *(const bf16x8*)(&img[rowi[d]][c0]) : zv;
    carry[d] = (valid[d] && c0 > 0) ? b2f(img[rowi[d]][c0 - 1]) : 0.f;
  }
  float sq = 0.f;
#pragma unroll
  for (int j = 0; j < 4; ++j){
    float right0[4];
    if (j < 3){
#pragma unroll
      for (int d = 0; d < 4; ++d){
        nxt[d] = valid[d] ? *(const bf16x8*)(&img[rowi[d]][c0 + 8*(j+1)]) : zv;
        right0[d] = b2f((unsigned short)nxt[d][0]);
      }
    } else {
#pragma unroll
      for (int d = 0; d < 4; ++d)
        right0[d] = (valid[d] && (c0 + 32 < 128)) ? b2f(img[rowi[d]][c0 + 32]) : 0.f;
    }
    float f[4][8];
#pragma unroll
    for (int d = 0; d < 4; ++d)
#pragma unroll
      for (int i = 0; i < 8; ++i) f[d][i] = b2f((unsigned short)cur[d][i]);
#pragma unroll
    for (int rr = 0; rr < 2; ++rr){
      float o[8];
#pragma unroll
      for (int cc = 0; cc < 8; ++cc){
        float a = 0.f;
#pragma unroll
        for (int d2 = 0; d2 < 3; ++d2){
          int d = rr + d2;
          float lf = (cc == 0) ? carry[d] : f[d][cc-1];
          float md = f[d][cc];
          float rt = (cc == 7) ? right0[d] : f[d][cc+1];
          a = fmaf(w9[d2*3+0], lf, a);
          a = fmaf(w9[d2*3+1], md, a);
          a = fmaf(w9[d2*3+2], rt, a);
        }
        o[cc] = a;
        sq = fmaf(a, a, sq);
      }
      bf16x8 ov;
#pragma unroll
      for (int cc = 0; cc < 8; ++cc) ov[cc] = (short)f2b(o[cc]);
      *(bf16x8*)(&outb[r0 + rr][c0 + 8*j]) = ov;
    }
#pragma unroll
    for (int d = 0; d < 4; ++d) carry[d] = f[d][7];
    if (j < 3){
#pragma unroll
      for (int d = 0; d < 4; ++d) cur[d] = nxt[d];
    }
  }
#pragma unroll
  for (int off = 32; off > 0; off >>= 1) sq += __shfl_xor(sq, off);
  if ((tid & 63) == 0) wred[tid >> 6] = sq;
  __syncthreads();
  for (int e = tid; e < 2048; e += 256){
    int row = e >> 4, p8 = (e & 15) * 8;
    *(bf16x8*)(base + row*IMGW + p8) = *(const bf16x8*)(&outb[row][p8]);
  }
  if (tid == 0)
    Nsq[((size_t)b*2 + t)*CDIM + c] = wred[0] + wred[1] + wred[2] + wred[3];
}

// ---- gram partials (R5 exact): S over px chunk of 2048, fragments from global
__global__ __launch_bounds__(256) void k_gram(const unsigned short* qd,
    const unsigned short* kd, float* Spart){
  __shared__ float S_lds[1024];
  int tid = threadIdx.x;
  int cs = blockIdx.x, h = blockIdx.y, b = blockIdx.z;
  int w = tid >> 6, l = tid & 63, lr = l & 15, lk = l >> 4;
  for (int e = tid; e < 1024; e += 256) S_lds[e] = 0.f;
  __syncthreads();
  const unsigned short* qb = qd + (size_t)(b*CDIM + h*32)*NPIX;
  const unsigned short* kb = kd + (size_t)(b*CDIM + h*32)*NPIX;
  f32x4 g4[2][2] = {};
  int pxb = cs*2048 + w*512 + lk*8;
#pragma unroll
  for (int kc = 0; kc < 16; ++kc){
    int px = pxb + kc*32;
    bf16x8 a0 = *(const bf16x8*)(qb + (size_t)lr*NPIX + px);
    bf16x8 a1 = *(const bf16x8*)(qb + (size_t)(16+lr)*NPIX + px);
    bf16x8 b0 = *(const bf16x8*)(kb + (size_t)lr*NPIX + px);
    bf16x8 b1 = *(const bf16x8*)(kb + (size_t)(16+lr)*NPIX + px);
    g4[0][0] = MF(a0, b0, g4[0][0]);
    g4[0][1] = MF(a0, b1, g4[0][1]);
    g4[1][0] = MF(a1, b0, g4[1][0]);
    g4[1][1] = MF(a1, b1, g4[1][1]);
  }
  for (int wv = 0; wv < 4; ++wv){
    if (w == wv){
#pragma unroll
      for (int mi = 0; mi < 2; ++mi)
#pragma unroll
        for (int ni = 0; ni < 2; ++ni)
#pragma unroll
          for (int r = 0; r < 4; ++r)
            S_lds[(mi*16 + lk*4 + r)*32 + ni*16 + lr] += g4[mi][ni][r];
    }
    __syncthreads();
  }
  int bidx = (b*NHEADS + h)*8 + cs;
  for (int e = tid; e < 1024; e += 256) Spart[(size_t)bidx*1024 + e] = S_lds[e];
}

// ---- reduce partials, l2norm scaling + rescale, softmax rows (R5 exact)
__global__ __launch_bounds__(256) void k_attn(const float* Spart, const float* Nsq,
    const void* rescale, float* attnG, const int* flag){
  __shared__ float S[1024];
  __shared__ float rn[64];
  int bh = blockIdx.x, tid = threadIdx.x;
  int b = bh / NHEADS, h = bh % NHEADS;
  int isbf = *flag;
  for (int e = tid; e < 1024; e += 256){
    float a = 0.f;
    for (int st = 0; st < 8; ++st) a += Spart[((size_t)bh*8 + st)*1024 + e];
    S[e] = a;
  }
  if (tid < 64){
    int t = tid >> 5, ch = h*32 + (tid & 31);
    float a = Nsq[((size_t)b*2 + t)*CDIM + ch];
    rn[tid] = 1.f / fmaxf(sqrtf(a), 1e-12f);
  }
  __syncthreads();
  if (tid < 32){
    float sc = ldT(rescale, h, isbf);
    float lo[32], mx = -1e30f;
#pragma unroll
    for (int d = 0; d < 32; ++d){
      lo[d] = S[tid*32 + d] * rn[tid] * rn[32 + d] * sc;
      mx = fmaxf(mx, lo[d]);
    }
    float sum = 0.f;
#pragma unroll
    for (int d = 0; d < 32; ++d){ lo[d] = __expf(lo[d] - mx); sum += lo[d]; }
    float inv = 1.f / sum;
#pragma unroll
    for (int d = 0; d < 32; ++d) attnG[(size_t)bh*1024 + tid*32 + d] = lo[d] * inv;
  }
}

// ---- M[b] = Wp @ blockdiag(attn[b])  (R5 exact)
__global__ __launch_bounds__(256) void k_mmat(const void* Wp, const float* attnG,
    unsigned short* Mb, const int* flag){
  __shared__ float at[NHEADS*1024];
  __shared__ float wp[32][200];
  int b = blockIdx.x, og = blockIdx.y, tid = threadIdx.x;
  int isbf = *flag;
  for (int e = tid; e < NHEADS*1024; e += 256) at[e] = attnG[(size_t)b*NHEADS*1024 + e];
  for (int e = tid; e < 32*192; e += 256){
    int r = e / 192, cdx = e % 192;
    wp[r][cdx] = ldT(Wp, (size_t)(og*32 + r)*CDIM + cdx, isbf);
  }
  __syncthreads();
  int r = tid >> 3, cg = tid & 7;
#pragma unroll 1
  for (int i = 0; i < 24; ++i){
    int dg = cg*24 + i;
    int hh = dg >> 5, d = dg & 31;
    float a = 0.f;
#pragma unroll
    for (int cc = 0; cc < 32; ++cc)
      a += wp[r][hh*32 + cc] * at[hh*1024 + cc*32 + d];
    Mb[(size_t)b*CDIM*CDIM + (size_t)(og*32 + r)*CDIM + dg] = f2b(a);
  }
}

// ---- final: out[b] = M[b] @ dw(v)[b]. R11: dw(v) computed on the fly while
// staging Bt (raw v0 rows r-1..r+1 are L2/L3-warm; same bf16 rounding point).
__global__ __launch_bounds__(256) void k_out(const unsigned short* v, const unsigned short* Mb,
    const void* wvd, void* out, const int* flag){
  __shared__ unsigned short Bt[64][200];
  __shared__ unsigned short outb[192][72];
  int tid = threadIdx.x;
  int ntr = blockIdx.x, b = blockIdx.y;
  int nt = (ntr & 7)*32 + (ntr >> 3);
  int n0 = nt * 64;
  int row = n0 >> 7;          // image row of this tile
  int isbf = *flag;
  // stage Bt[px][c^s] = dwconv3x3(v)[c][row][n0+px]
  for (int e = tid; e < 384; e += 256){
    int c = e >> 1, half = e & 1;
    int p0 = (n0 & 127) + half*32;        // col start within row
    float w9[9];
#pragma unroll
    for (int q = 0; q < 9; ++q) w9[q] = ldT(wvd, (size_t)c*9 + q, isbf);
    const unsigned short* vb = v + (size_t)(b*CDIM + c)*NPIX + row*IMGW;
#pragma unroll 1
    for (int jc = 0; jc < 4; ++jc){
      int c0 = p0 + jc*8;
      float o[8] = {0.f,0.f,0.f,0.f,0.f,0.f,0.f,0.f};
#pragma unroll
      for (int dr = 0; dr < 3; ++dr){
        int rr = row - 1 + dr;
        if (rr >= 0 && rr < 128){
          const unsigned short* rp = vb + (dr-1)*IMGW;
          bf16x8 bv = *(const bf16x8*)(rp + c0);
          float fl[10];
          fl[0] = (c0 > 0)       ? b2f(rp[c0-1]) : 0.f;
#pragma unroll
          for (int i = 0; i < 8; ++i) fl[1+i] = b2f((unsigned short)bv[i]);
          fl[9] = (c0 + 8 < 128) ? b2f(rp[c0+8]) : 0.f;
#pragma unroll
          for (int d = 0; d < 3; ++d){
            float wv = w9[dr*3+d];
#pragma unroll
            for (int i = 0; i < 8; ++i) o[i] = fmaf(wv, fl[i+d], o[i]);
          }
        }
      }
#pragma unroll
      for (int i = 0; i < 8; ++i){
        int px = half*32 + jc*8 + i;
        int s = ((px >> 3) & 7) << 3;
        Bt[px][c ^ s] = f2b(o[i]);
      }
    }
  }
  __syncthreads();
  int w = tid >> 6, l = tid & 63, lr = l & 15, lk = l >> 4;
  const unsigned short* A = Mb + (size_t)b*CDIM*CDIM;
  f32x4 acc[3][4] = {};
  for (int kc = 0; kc < 6; ++kc){
    bf16x8 af[3];
#pragma unroll
    for (int g = 0; g < 3; ++g)
      af[g] = *(const bf16x8*)(A + (size_t)(g*64 + w*16 + lr)*CDIM + kc*32 + lk*8);
#pragma unroll
    for (int nf = 0; nf < 4; ++nf){
      int nrow = nf*16 + lr;
      int s = ((nrow >> 3) & 7) << 3;
      bf16x8 bfv = *(const bf16x8*)(&Bt[nrow][(kc*32 + lk*8) ^ s]);
#pragma unroll
      for (int g = 0; g < 3; ++g) acc[g][nf] = MF(af[g], bfv, acc[g][nf]);
    }
  }
  int isbf2 = *flag;
  if (isbf2){
#pragma unroll
    for (int g = 0; g < 3; ++g)
#pragma unroll
      for (int nf = 0; nf < 4; ++nf)
#pragma unroll
        for (int r = 0; r < 4; ++r)
          outb[g*64 + w*16 + lk*4 + r][nf*16 + lr] = f2b(acc[g][nf][r]);
    __syncthreads();
    unsigned short* dst = (unsigned short*)out + (size_t)b*CDIM*NPIX;
    for (int e = tid; e < 1536; e += 256){
      int m = e >> 3, p8 = (e & 7) * 8;
      *(bf16x8*)(dst + (size_t)m*NPIX + n0 + p8) = *(const bf16x8*)(&outb[m][p8]);
    }
  } else {
#pragma unroll
    for (int g = 0; g < 3; ++g)
#pragma unroll
      for (int nf = 0; nf < 4; ++nf)
#pragma unroll
        for (int r = 0; r < 4; ++r){
          int m = g*64 + w*16 + lk*4 + r;
          ((float*)out)[(size_t)(b*CDIM + m)*NPIX + n0 + nf*16 + lr] = acc[g][nf][r];
        }
  }
}

extern "C" void kernel_launch(void* const* d_in, const int* in_sizes, int n_in,
                              void* d_out, int out_size, void* d_ws, size_t ws_size,
                              hipStream_t stream){
  const void* x   = d_in[0];
  const void* Wq  = d_in[1];
  const void* Wk  = d_in[2];
  const void* Wv  = d_in[3];
  const void* Wqd = d_in[4];
  const void* Wkd = d_in[5];
  const void* Wvd = d_in[6];
  const void* rsc = d_in[7];
  const void* Wp  = d_in[8];

  char* ws = (char*)d_ws;
  size_t o = 0;
  int* flag             = (int*)(ws + o);            o += 256;
  unsigned short* Wqkv  = (unsigned short*)(ws + o); o += (size_t)576*192*2;
  unsigned short* q0    = (unsigned short*)(ws + o); o += (size_t)NB*CDIM*NPIX*2;
  unsigned short* k0    = (unsigned short*)(ws + o); o += (size_t)NB*CDIM*NPIX*2;
  unsigned short* v0    = (unsigned short*)(ws + o); o += (size_t)NB*CDIM*NPIX*2;
  float* Spart          = (float*)(ws + o);          o += (size_t)384*1024*4;
  float* Nsq            = (float*)(ws + o);          o += (size_t)NB*2*CDIM*4;
  float* attnG          = (float*)(ws + o);          o += (size_t)48*1024*4;
  unsigned short* Mb    = (unsigned short*)(ws + o); o += (size_t)NB*CDIM*CDIM*2;

  k_detect<<<dim3(1), 64, 0, stream>>>((const unsigned short*)x, flag);
  k_prep  <<<dim3(432), 256, 0, stream>>>(Wq, Wk, Wv, Wqkv, flag);
  k_conv1 <<<dim3(256, NB), 256, 0, stream>>>(x, Wqkv, q0, k0, v0, flag);
  k_dw    <<<dim3(2, CDIM, NB), 256, 0, stream>>>(q0, k0, Wqd, Wkd, Nsq, flag);
  k_gram  <<<dim3(8, NHEADS, NB), 256, 0, stream>>>(q0, k0, Spart);
  k_attn  <<<dim3(48), 256, 0, stream>>>(Spart, Nsq, rsc, attnG, flag);
  k_mmat  <<<dim3(NB, 6), 256, 0, stream>>>(Wp, attnG, Mb, flag);
  k_out   <<<dim3(256, NB), 256, 0, stream>>>(v0, Mb, Wvd, d_out, flag);
}

// Round 12
// 260.383 us; speedup vs baseline: 1.1137x; 1.1137x over previous
//
#include <hip/hip_runtime.h>
#include <hip/hip_bf16.h>

// Spectral_Atten: q,k,v = dwconv3x3(conv1x1(x,W*)); channel-attention per head;
// out = conv1x1(attn@v, Wp).
// R1: split latency-bound fused dwgram (554->398). R2: k_mmat retile (->281).
// R3-R11: systematic falsification: store patterns, XCD locality, bank
//   conflicts, occupancy, in-loop load latency all individually disproven for
//   conv1 (~111us across 6 structures); fusions (R6 dwg, R11 k_out-dw) lose
//   via occupancy/serial-preamble. R8/R9: regalloc spill traps.
// R12: exact restore of R5 -- the verified best (260us).

using bf16x8 = __attribute__((ext_vector_type(8))) short;
using f32x4  = __attribute__((ext_vector_type(4))) float;
using fvec4  = __attribute__((ext_vector_type(4))) float;

#define NB     8
#define CDIM   192
#define NHEADS 6
#define IMGW   128
#define NPIX   16384

__device__ __forceinline__ float b2f(unsigned short u){
  return __uint_as_float(((unsigned int)u) << 16);
}
__device__ __forceinline__ unsigned short f2b(float f){
  unsigned int x = __float_as_uint(f);
  return (unsigned short)((x + 0x7FFFu + ((x >> 16) & 1u)) >> 16);
}
__device__ __forceinline__ float ldT(const void* p, size_t i, int isbf){
  return isbf ? b2f(((const unsigned short*)p)[i]) : ((const float*)p)[i];
}
__device__ __forceinline__ f32x4 MF(bf16x8 a, bf16x8 b, f32x4 c){
  return __builtin_amdgcn_mfma_f32_16x16x32_bf16(a, b, c, 0, 0, 0);
}

// ---- dtype detector (bf16 vs fp32 device buffers)
__global__ void k_detect(const unsigned short* x, int* flag){
  int l = threadIdx.x;
  int cnt = 0;
#pragma unroll
  for (int i = 0; i < 2; ++i){
    unsigned short u = x[(l*2 + i)*2];
    float a = fabsf(b2f(u));
    if (a == 0.f || (a > 1e-4f && a < 20.f)) ++cnt;
  }
  int tot = __popcll(__ballot(cnt >= 1)) + __popcll(__ballot(cnt >= 2));
  if (l == 0) *flag = (tot > 64) ? 1 : 0;
}

// ---- pack Wq,Wk,Wv into stacked bf16 [576][192]
__global__ __launch_bounds__(256) void k_prep(const void* Wq, const void* Wk, const void* Wv,
    unsigned short* Wqkv, const int* flag){
  int i = blockIdx.x*256 + threadIdx.x;
  if (i >= 576*192) return;
  int isbf = *flag;
  int m = i / 192, kk = i % 192;
  int t = m / 192;
  const void* W = (t == 0) ? Wq : (t == 1) ? Wk : Wv;
  Wqkv[i] = f2b(ldT(W, (size_t)(m % 192)*192 + kk, isbf));
}

// ---- fused triple 1x1 conv: q0,k0,v0 (bf16) = W{q,k,v} @ x[b].
// XCD swizzle on nt; XOR-swizzled transposed staging; LDS epilogue.
__global__ __launch_bounds__(256) void k_conv1(const void* x, const unsigned short* Wqkv,
    unsigned short* q0, unsigned short* k0, unsigned short* v0, const int* flag){
  __shared__ unsigned short Bt[64][200];     // x-tile [px][k^s], s=((px>>3)&7)<<3
  __shared__ unsigned short outb[192][72];   // epilogue tile [m][px]
  int tid = threadIdx.x;
  int ntr = blockIdx.x, b = blockIdx.y;
  int nt = (ntr & 7)*32 + (ntr >> 3);        // XCD-bijective: 32 contiguous tiles/XCD
  int n0 = nt * 64;
  int isbf = *flag;
  if (isbf){
    const unsigned short* xs = (const unsigned short*)x;
    for (int r = tid; r < 1536; r += 256){
      int k = r >> 3, j8 = (r & 7) * 8;
      int s = (r & 7) << 3;                  // = ((n>>3)&7)<<3 for n in [j8,j8+8)
      bf16x8 v = *(const bf16x8*)(xs + (size_t)(b*CDIM + k)*NPIX + n0 + j8);
      int kx = k ^ s;
#pragma unroll
      for (int i = 0; i < 8; ++i) Bt[j8+i][kx] = (unsigned short)v[i];
    }
  } else {
    const float* xf = (const float*)x;
    for (int r = tid; r < 3072; r += 256){
      int k = r >> 4, j4 = (r & 15) * 4;
      int s = ((j4 >> 3) & 7) << 3;
      fvec4 v = *(const fvec4*)(xf + (size_t)(b*CDIM + k)*NPIX + n0 + j4);
      int kx = k ^ s;
#pragma unroll
      for (int i = 0; i < 4; ++i) Bt[j4+i][kx] = f2b(v[i]);
    }
  }
  __syncthreads();
  int w = tid >> 6, l = tid & 63, lr = l & 15, lk = l >> 4;
#pragma unroll 1
  for (int t = 0; t < 3; ++t){
    f32x4 acc[3][4] = {};
    for (int kc = 0; kc < 6; ++kc){
      bf16x8 af[3];
#pragma unroll
      for (int g = 0; g < 3; ++g)
        af[g] = *(const bf16x8*)(Wqkv + ((size_t)t*CDIM + g*64 + w*16 + lr)*CDIM + kc*32 + lk*8);
#pragma unroll
      for (int nf = 0; nf < 4; ++nf){
        int nrow = nf*16 + lr;
        int s = ((nrow >> 3) & 7) << 3;
        bf16x8 bfv = *(const bf16x8*)(&Bt[nrow][(kc*32 + lk*8) ^ s]);
#pragma unroll
        for (int g = 0; g < 3; ++g) acc[g][nf] = MF(af[g], bfv, acc[g][nf]);
      }
    }
    __syncthreads();   // prev t's cooperative store done; outb free
#pragma unroll
    for (int g = 0; g < 3; ++g)
#pragma unroll
      for (int nf = 0; nf < 4; ++nf)
#pragma unroll
        for (int r = 0; r < 4; ++r)
          outb[g*64 + w*16 + lk*4 + r][nf*16 + lr] = f2b(acc[g][nf][r]);
    __syncthreads();
    unsigned short* dst = ((t == 0) ? q0 : (t == 1) ? k0 : v0) + (size_t)b*CDIM*NPIX;
    for (int e = tid; e < 1536; e += 256){
      int m = e >> 3, p8 = (e & 7) * 8;
      *(bf16x8*)(dst + (size_t)m*NPIX + n0 + p8) = *(const bf16x8*)(&outb[m][p8]);
    }
  }
}

// ---- depthwise 3x3, in-place on q0/k0/v0; per-(b,t,c) sum-of-squares for q,k.
__global__ __launch_bounds__(256) void k_dw(unsigned short* q0, unsigned short* k0,
    unsigned short* v0, const void* wqd, const void* wkd, const void* wvd,
    float* Nsq, const int* flag){
  __shared__ unsigned short img[128][136];
  __shared__ unsigned short outb[128][136];
  __shared__ float wred[4];
  int tid = threadIdx.x;
  int t = blockIdx.x, c = blockIdx.y, b = blockIdx.z;
  int isbf = *flag;
  unsigned short* base = ((t == 0) ? q0 : (t == 1) ? k0 : v0) + (size_t)(b*CDIM + c)*NPIX;
  const void* wd = (t == 0) ? wqd : (t == 1) ? wkd : wvd;
  float w9[9];
#pragma unroll
  for (int e = 0; e < 9; ++e) w9[e] = ldT(wd, (size_t)c*9 + e, isbf);
  for (int r = tid; r < 2048; r += 256){
    int row = r >> 4, col8 = (r & 15)*8;
    *(bf16x8*)(&img[row][col8]) = *(const bf16x8*)(base + row*IMGW + col8);
  }
  __syncthreads();
  int tr = tid >> 2, tc = tid & 3;
  int c0 = tc * 32, r0 = tr * 2;
  const bf16x8 zv = {0,0,0,0,0,0,0,0};
  int  rowi[4]; bool valid[4];
  bf16x8 cur[4], nxt[4];
  float carry[4];
#pragma unroll
  for (int d = 0; d < 4; ++d){
    rowi[d] = r0 - 1 + d;
    valid[d] = (rowi[d] >= 0) && (rowi[d] < 128);
    cur[d] = valid[d] ? *(const bf16x8*)(&img[rowi[d]][c0]) : zv;
    carry[d] = (valid[d] && c0 > 0) ? b2f(img[rowi[d]][c0 - 1]) : 0.f;
  }
  float sq = 0.f;
#pragma unroll
  for (int j = 0; j < 4; ++j){
    float right0[4];
    if (j < 3){
#pragma unroll
      for (int d = 0; d < 4; ++d){
        nxt[d] = valid[d] ? *(const bf16x8*)(&img[rowi[d]][c0 + 8*(j+1)]) : zv;
        right0[d] = b2f((unsigned short)nxt[d][0]);
      }
    } else {
#pragma unroll
      for (int d = 0; d < 4; ++d)
        right0[d] = (valid[d] && (c0 + 32 < 128)) ? b2f(img[rowi[d]][c0 + 32]) : 0.f;
    }
    float f[4][8];
#pragma unroll
    for (int d = 0; d < 4; ++d)
#pragma unroll
      for (int i = 0; i < 8; ++i) f[d][i] = b2f((unsigned short)cur[d][i]);
#pragma unroll
    for (int rr = 0; rr < 2; ++rr){
      float o[8];
#pragma unroll
      for (int cc = 0; cc < 8; ++cc){
        float a = 0.f;
#pragma unroll
        for (int d2 = 0; d2 < 3; ++d2){
          int d = rr + d2;
          float lf = (cc == 0) ? carry[d] : f[d][cc-1];
          float md = f[d][cc];
          float rt = (cc == 7) ? right0[d] : f[d][cc+1];
          a = fmaf(w9[d2*3+0], lf, a);
          a = fmaf(w9[d2*3+1], md, a);
          a = fmaf(w9[d2*3+2], rt, a);
        }
        o[cc] = a;
        if (t < 2) sq = fmaf(a, a, sq);
      }
      bf16x8 ov;
#pragma unroll
      for (int cc = 0; cc < 8; ++cc) ov[cc] = (short)f2b(o[cc]);
      *(bf16x8*)(&outb[r0 + rr][c0 + 8*j]) = ov;
    }
#pragma unroll
    for (int d = 0; d < 4; ++d) carry[d] = f[d][7];
    if (j < 3){
#pragma unroll
      for (int d = 0; d < 4; ++d) cur[d] = nxt[d];
    }
  }
  if (t < 2){
#pragma unroll
    for (int off = 32; off > 0; off >>= 1) sq += __shfl_xor(sq, off);
    if ((tid & 63) == 0) wred[tid >> 6] = sq;
  }
  __syncthreads();
  for (int e = tid; e < 2048; e += 256){
    int row = e >> 4, p8 = (e & 15) * 8;
    *(bf16x8*)(base + row*IMGW + p8) = *(const bf16x8*)(&outb[row][p8]);
  }
  if (t < 2 && tid == 0)
    Nsq[((size_t)b*2 + t)*CDIM + c] = wred[0] + wred[1] + wred[2] + wred[3];
}

// ---- gram partials: S over px chunk of 2048, MFMA fragments from global
__global__ __launch_bounds__(256) void k_gram(const unsigned short* qd,
    const unsigned short* kd, float* Spart){
  __shared__ float S_lds[1024];
  int tid = threadIdx.x;
  int cs = blockIdx.x, h = blockIdx.y, b = blockIdx.z;
  int w = tid >> 6, l = tid & 63, lr = l & 15, lk = l >> 4;
  for (int e = tid; e < 1024; e += 256) S_lds[e] = 0.f;
  __syncthreads();
  const unsigned short* qb = qd + (size_t)(b*CDIM + h*32)*NPIX;
  const unsigned short* kb = kd + (size_t)(b*CDIM + h*32)*NPIX;
  f32x4 g4[2][2] = {};
  int pxb = cs*2048 + w*512 + lk*8;
#pragma unroll
  for (int kc = 0; kc < 16; ++kc){
    int px = pxb + kc*32;
    bf16x8 a0 = *(const bf16x8*)(qb + (size_t)lr*NPIX + px);
    bf16x8 a1 = *(const bf16x8*)(qb + (size_t)(16+lr)*NPIX + px);
    bf16x8 b0 = *(const bf16x8*)(kb + (size_t)lr*NPIX + px);
    bf16x8 b1 = *(const bf16x8*)(kb + (size_t)(16+lr)*NPIX + px);
    g4[0][0] = MF(a0, b0, g4[0][0]);
    g4[0][1] = MF(a0, b1, g4[0][1]);
    g4[1][0] = MF(a1, b0, g4[1][0]);
    g4[1][1] = MF(a1, b1, g4[1][1]);
  }
  for (int wv = 0; wv < 4; ++wv){
    if (w == wv){
#pragma unroll
      for (int mi = 0; mi < 2; ++mi)
#pragma unroll
        for (int ni = 0; ni < 2; ++ni)
#pragma unroll
          for (int r = 0; r < 4; ++r)
            S_lds[(mi*16 + lk*4 + r)*32 + ni*16 + lr] += g4[mi][ni][r];
    }
    __syncthreads();
  }
  int bidx = (b*NHEADS + h)*8 + cs;
  for (int e = tid; e < 1024; e += 256) Spart[(size_t)bidx*1024 + e] = S_lds[e];
}

// ---- reduce partials, l2norm scaling + rescale, softmax rows
__global__ __launch_bounds__(256) void k_attn(const float* Spart, const float* Nsq,
    const void* rescale, float* attnG, const int* flag){
  __shared__ float S[1024];
  __shared__ float rn[64];
  int bh = blockIdx.x, tid = threadIdx.x;
  int b = bh / NHEADS, h = bh % NHEADS;
  int isbf = *flag;
  for (int e = tid; e < 1024; e += 256){
    float a = 0.f;
    for (int st = 0; st < 8; ++st) a += Spart[((size_t)bh*8 + st)*1024 + e];
    S[e] = a;
  }
  if (tid < 64){
    int t = tid >> 5, ch = h*32 + (tid & 31);
    float a = Nsq[((size_t)b*2 + t)*CDIM + ch];
    rn[tid] = 1.f / fmaxf(sqrtf(a), 1e-12f);
  }
  __syncthreads();
  if (tid < 32){
    float sc = ldT(rescale, h, isbf);
    float lo[32], mx = -1e30f;
#pragma unroll
    for (int d = 0; d < 32; ++d){
      lo[d] = S[tid*32 + d] * rn[tid] * rn[32 + d] * sc;
      mx = fmaxf(mx, lo[d]);
    }
    float sum = 0.f;
#pragma unroll
    for (int d = 0; d < 32; ++d){ lo[d] = __expf(lo[d] - mx); sum += lo[d]; }
    float inv = 1.f / sum;
#pragma unroll
    for (int d = 0; d < 32; ++d) attnG[(size_t)bh*1024 + tid*32 + d] = lo[d] * inv;
  }
}

// ---- M[b] = Wp @ blockdiag(attn[b])  -- 48 blocks, LDS-staged operands.
__global__ __launch_bounds__(256) void k_mmat(const void* Wp, const float* attnG,
    unsigned short* Mb, const int* flag){
  __shared__ float at[NHEADS*1024];
  __shared__ float wp[32][200];
  int b = blockIdx.x, og = blockIdx.y, tid = threadIdx.x;
  int isbf = *flag;
  for (int e = tid; e < NHEADS*1024; e += 256) at[e] = attnG[(size_t)b*NHEADS*1024 + e];
  for (int e = tid; e < 32*192; e += 256){
    int r = e / 192, cdx = e % 192;
    wp[r][cdx] = ldT(Wp, (size_t)(og*32 + r)*CDIM + cdx, isbf);
  }
  __syncthreads();
  int r = tid >> 3, cg = tid & 7;
#pragma unroll 1
  for (int i = 0; i < 24; ++i){
    int dg = cg*24 + i;
    int hh = dg >> 5, d = dg & 31;
    float a = 0.f;
#pragma unroll
    for (int cc = 0; cc < 32; ++cc)
      a += wp[r][hh*32 + cc] * at[hh*1024 + cc*32 + d];
    Mb[(size_t)b*CDIM*CDIM + (size_t)(og*32 + r)*CDIM + dg] = f2b(a);
  }
}

// ---- final: out[b] = M[b] @ v[b]. XCD swizzle + XOR-swizzled staging.
__global__ __launch_bounds__(256) void k_out(const unsigned short* v, const unsigned short* Mb,
    void* out, const int* flag){
  __shared__ unsigned short Bt[64][200];
  __shared__ unsigned short outb[192][72];
  int tid = threadIdx.x;
  int ntr = blockIdx.x, b = blockIdx.y;
  int nt = (ntr & 7)*32 + (ntr >> 3);
  int n0 = nt * 64;
  for (int r = tid; r < 1536; r += 256){
    int k = r >> 3, j8 = (r & 7) * 8;
    int s = (r & 7) << 3;
    bf16x8 vv = *(const bf16x8*)(v + (size_t)(b*CDIM + k)*NPIX + n0 + j8);
    int kx = k ^ s;
#pragma unroll
    for (int i = 0; i < 8; ++i) Bt[j8+i][kx] = (unsigned short)vv[i];
  }
  __syncthreads();
  int w = tid >> 6, l = tid & 63, lr = l & 15, lk = l >> 4;
  const unsigned short* A = Mb + (size_t)b*CDIM*CDIM;
  f32x4 acc[3][4] = {};
  for (int kc = 0; kc < 6; ++kc){
    bf16x8 af[3];
#pragma unroll
    for (int g = 0; g < 3; ++g)
      af[g] = *(const bf16x8*)(A + (size_t)(g*64 + w*16 + lr)*CDIM + kc*32 + lk*8);
#pragma unroll
    for (int nf = 0; nf < 4; ++nf){
      int nrow = nf*16 + lr;
      int s = ((nrow >> 3) & 7) << 3;
      bf16x8 bfv = *(const bf16x8*)(&Bt[nrow][(kc*32 + lk*8) ^ s]);
#pragma unroll
      for (int g = 0; g < 3; ++g) acc[g][nf] = MF(af[g], bfv, acc[g][nf]);
    }
  }
  int isbf = *flag;
  if (isbf){
#pragma unroll
    for (int g = 0; g < 3; ++g)
#pragma unroll
      for (int nf = 0; nf < 4; ++nf)
#pragma unroll
        for (int r = 0; r < 4; ++r)
          outb[g*64 + w*16 + lk*4 + r][nf*16 + lr] = f2b(acc[g][nf][r]);
    __syncthreads();
    unsigned short* dst = (unsigned short*)out + (size_t)b*CDIM*NPIX;
    for (int e = tid; e < 1536; e += 256){
      int m = e >> 3, p8 = (e & 7) * 8;
      *(bf16x8*)(dst + (size_t)m*NPIX + n0 + p8) = *(const bf16x8*)(&outb[m][p8]);
    }
  } else {
#pragma unroll
    for (int g = 0; g < 3; ++g)
#pragma unroll
      for (int nf = 0; nf < 4; ++nf)
#pragma unroll
        for (int r = 0; r < 4; ++r){
          int m = g*64 + w*16 + lk*4 + r;
          ((float*)out)[(size_t)(b*CDIM + m)*NPIX + n0 + nf*16 + lr] = acc[g][nf][r];
        }
  }
}

extern "C" void kernel_launch(void* const* d_in, const int* in_sizes, int n_in,
                              void* d_out, int out_size, void* d_ws, size_t ws_size,
                              hipStream_t stream){
  const void* x   = d_in[0];
  const void* Wq  = d_in[1];
  const void* Wk  = d_in[2];
  const void* Wv  = d_in[3];
  const void* Wqd = d_in[4];
  const void* Wkd = d_in[5];
  const void* Wvd = d_in[6];
  const void* rsc = d_in[7];
  const void* Wp  = d_in[8];

  char* ws = (char*)d_ws;
  size_t o = 0;
  int* flag             = (int*)(ws + o);            o += 256;
  unsigned short* Wqkv  = (unsigned short*)(ws + o); o += (size_t)576*192*2;
  unsigned short* q0    = (unsigned short*)(ws + o); o += (size_t)NB*CDIM*NPIX*2;
  unsigned short* k0    = (unsigned short*)(ws + o); o += (size_t)NB*CDIM*NPIX*2;
  unsigned short* v0    = (unsigned short*)(ws + o); o += (size_t)NB*CDIM*NPIX*2;
  float* Spart          = (float*)(ws + o);          o += (size_t)384*1024*4;
  float* Nsq            = (float*)(ws + o);          o += (size_t)NB*2*CDIM*4;
  float* attnG          = (float*)(ws + o);          o += (size_t)48*1024*4;
  unsigned short* Mb    = (unsigned short*)(ws + o); o += (size_t)NB*CDIM*CDIM*2;

  k_detect<<<dim3(1), 64, 0, stream>>>((const unsigned short*)x, flag);
  k_prep  <<<dim3(432), 256, 0, stream>>>(Wq, Wk, Wv, Wqkv, flag);
  k_conv1 <<<dim3(256, NB), 256, 0, stream>>>(x, Wqkv, q0, k0, v0, flag);
  k_dw    <<<dim3(3, CDIM, NB), 256, 0, stream>>>(q0, k0, v0, Wqd, Wkd, Wvd, Nsq, flag);
  k_gram  <<<dim3(8, NHEADS, NB), 256, 0, stream>>>(q0, k0, Spart);
  k_attn  <<<dim3(48), 256, 0, stream>>>(Spart, Nsq, rsc, attnG, flag);
  k_mmat  <<<dim3(NB, 6), 256, 0, stream>>>(Wp, attnG, Mb, flag);
  k_out   <<<dim3(256, NB), 256, 0, stream>>>(v0, Mb, d_out, flag);
}